// Round 11
// baseline (182.358 us; speedup 1.0000x reference)
//
#include <hip/hip_runtime.h>
#include <cstdint>
#include <cmath>

typedef int  v4i  __attribute__((ext_vector_type(4)));
typedef int  v16i __attribute__((ext_vector_type(16)));
typedef unsigned int u32x4 __attribute__((ext_vector_type(4)));

// ---- d_ws layout (4-byte words) ----
// Thresholds on popcount stored as negthr = -(thr+1):  pc <= thr  <=>  (pc + negthr) < 0
// Thresholds on c (MFMA path) stored as nthr2 = -ceil(t):  c >= t  <=>  (c + nthr2) >= 0
#define OFF_W1   0      // 32  u32: conv1 weight bits (27 bits: c*9+dy*3+dx)
#define OFF_T1   32     // 32  i32: conv1 negthr (popcount domain)
#define OFF_W3   384    // 576 u32: conv3 weight bits [o][k]
#define OFF_T3   960    // 64  i32: conv3 negthr (popcount domain)
#define OFF_WFC1 1024   // 256 u32: fc1 weight bits, 2 words per output (64 bits)
#define OFF_A4   1280   // 128 f32: h = clip(pc*a4 + c4, -1, 1)
#define OFF_C4   1408   // 128 f32
#define OFF_WF2  1536   // 256 f32: w_fc2 [2][128]
#define OFF_WF3  1792   // 512 f32: w_fc3 [4][128]
#define OFF_BN5  2304   // 4 f32: inv5[2], d5[2]
#define OFF_BN6  2308   // 8 f32: inv6[4], d6[4]
#define OFF_B2   2560   // 2304 u32: conv2 i8-MFMA B frags [s:9][lane:64][reg:4], bytes = +-1
#define OFF_T2C  4864   // 32  i32: conv2 nthr2 = -ceil(t) on preactivation c

__device__ __forceinline__ int thr_neg(double nterms, double g, double b, double m, double v) {
    double inv = g / sqrt(v + 1e-5);
    double t = m - b / inv;                   // bit=1  <=>  c >= t   (inv > 0)
    double thr = floor((nterms - t) * 0.5);   // c = nterms - 2*pc  =>  pc <= thr
    if (thr < -2147000000.0) thr = -2147000000.0;
    if (thr >  2147000000.0) thr =  2147000000.0;
    return -((int)thr + 1);                   // sign(pc + negthr) == (pc <= thr)
}

// threshold directly on integer preactivation c: bit = (c >= t) <=> (c >= ceil(t))
__device__ __forceinline__ int thr_c_neg(double g, double b, double m, double v) {
    double inv = g / sqrt(v + 1e-5);
    double t = m - b / inv;                   // inv > 0 in this problem (gamma in [0.5,1.5])
    double ct = ceil(t);
    if (ct < -2147000000.0) ct = -2147000000.0;
    if (ct >  2147000000.0) ct =  2147000000.0;
    return -(int)ct;                          // c + nthr2 >= 0  <=>  bit = 1
}

// 5 blocks x 256 threads. Coalesced global->LDS staging, then pack from LDS.
__global__ void k_prep(const float* __restrict__ w1, const float* __restrict__ w2,
                       const float* __restrict__ w3, const float* __restrict__ wfc1,
                       const float* __restrict__ wfc2, const float* __restrict__ wfc3,
                       const float* __restrict__ bn1, const float* __restrict__ bn2,
                       const float* __restrict__ bn3, const float* __restrict__ bn4,
                       const float* __restrict__ bn5, const float* __restrict__ bn6,
                       unsigned int* __restrict__ ws) {
    __shared__ float stage[9216];
    int t = threadIdx.x;
    int blk = blockIdx.x;
    float* wsf = (float*)ws;
    int*   wsi = (int*)ws;

    if (blk == 0) {
        for (int i = t; i < 864; i += 256) stage[i] = w1[i];
        __syncthreads();
        if (t < 32) {
            unsigned int bits = 0;
            for (int j = 0; j < 27; ++j) bits |= (stage[t*27+j] >= 0.f ? 1u : 0u) << j;
            ws[OFF_W1 + t] = bits;
            wsi[OFF_T1 + t]  = thr_neg(27.0, bn1[t], bn1[32+t], bn1[64+t], bn1[96+t]);
            wsi[OFF_T2C + t] = thr_c_neg(bn2[t], bn2[32+t], bn2[64+t], bn2[96+t]);
        }
        for (int i = t; i < 256; i += 256) wsf[OFF_WF2 + i] = wfc2[i];
        for (int i = t; i < 512; i += 256) wsf[OFF_WF3 + i] = wfc3[i];
        if (t < 2) {
            float g = bn5[t], b = bn5[2+t], m = bn5[4+t], v = bn5[6+t];
            float inv = g / sqrtf(v + 1e-5f);
            wsf[OFF_BN5 + t]     = inv;
            wsf[OFF_BN5 + 2 + t] = b - m * inv;
        }
        if (t >= 4 && t < 8) {
            int j = t - 4;
            float g = bn6[j], b = bn6[4+j], m = bn6[8+j], v = bn6[12+j];
            float inv = g / sqrtf(v + 1e-5f);
            wsf[OFF_BN6 + j]     = inv;
            wsf[OFF_BN6 + 4 + j] = b - m * inv;
        }
    } else if (blk == 1) {
        // conv2 weights -> i8 MFMA B fragments (+-1 bytes), layout for
        // v_mfma_i32_32x32x32_i8: col = lane&31 = och, k = 16*(lane>>5) + reg*4 + byte,
        // global K order: k = (dy*3+dx)*32 + ic  (step s = dy*3+dx, K=288 = 9 steps)
        for (int i = t; i < 9216; i += 256) stage[i] = w2[i];
        __syncthreads();
        for (int idx = t; idx < 2304; idx += 256) {
            int s   = idx >> 8;          // K-step 0..8  (= dy*3+dx)
            int rem = idx & 255;
            int l   = rem >> 2;          // lane 0..63
            int reg = rem & 3;
            int och = l & 31;
            int icb = ((l >> 5) << 4) + (reg << 2);
            unsigned int wv = 0;
            #pragma unroll
            for (int j = 0; j < 4; ++j) {
                int ic = icb + j;
                unsigned int by = (stage[(och*32 + ic)*9 + s] >= 0.f) ? 0x01u : 0xFFu;
                wv |= by << (8*j);
            }
            ws[OFF_B2 + idx] = wv;
        }
    } else if (blk == 2 || blk == 3) {
        int base = (blk - 2) * 9216;
        for (int i = t; i < 9216; i += 256) stage[i] = w3[base + i];
        __syncthreads();
        for (int idx = t; idx < 288; idx += 256) {
            int o = idx / 9, k = idx - o*9;
            unsigned int bits = 0;
            for (int i = 0; i < 32; ++i)
                bits |= (stage[(o*32+i)*9 + k] >= 0.f ? 1u : 0u) << i;
            ws[OFF_W3 + base/32 + idx] = bits;   // base/32 = 0 or 288
        }
    } else {
        for (int i = t; i < 8192; i += 256) stage[i] = wfc1[i];
        __syncthreads();
        if (t < 128) {
            unsigned int lo = 0, hi = 0;
            for (int j = 0; j < 32; ++j) lo |= (stage[t*64+j]    >= 0.f ? 1u : 0u) << j;
            for (int j = 0; j < 32; ++j) hi |= (stage[t*64+32+j] >= 0.f ? 1u : 0u) << j;
            ws[OFF_WFC1 + 2*t]     = lo;
            ws[OFF_WFC1 + 2*t + 1] = hi;
            float g = bn4[t], b = bn4[128+t], m = bn4[256+t], v = bn4[384+t];
            float inv = g / sqrtf(v + 1e-5f);
            wsf[OFF_A4 + t] = -2.f * inv;                 // c = 64 - 2*pc
            wsf[OFF_C4 + t] = (64.f - m) * inv + b;
        }
        if (t >= 128 && t < 192) {
            int j = t - 128;
            wsi[OFF_T3 + j] = thr_neg(288.0, bn3[j], bn3[64+j], bn3[128+j], bn3[192+j]);
        }
    }
}

// 8 WAVES PER BLOCK (512 threads), one image per wave, PER-IMAGE DISPATCH.
// R10 post-mortem: this structure raised occupancy 35->60% (best of session),
// but launch_bounds(512,8) forced VGPR=32 -> 8.6MB scratch spill churn that
// cancelled the gain (VALUBusy stuck 65%, dur 57us). The body genuinely needs
// ~60-75 VGPR (R7/R8 measured unconstrained). Fix: the INTERMEDIATE tier —
// launch_bounds(512,6) caps VGPR at ~84: fits the body spill-free AND allows
// 6 waves/SIMD = 3 x 8-wave blocks/CU (LDS 38.4KB permits 4). WRITE_SIZE is
// the spill tripwire: must return to ~0.4MB.
// All inter-stage deps are wave-internal -> no barriers in the image body;
// the single __syncthreads covers the block-shared B staging only (before
// the bounds-exit, so no barrier divergence).
//
// LDS per wave slice (dwords), time-multiplexed:
//   [0..66)    inrow   (input sign bits)                 phase 1
//   [66..466)  c1      (conv1 sign words)                phase 2-3
//   [0..800)   bytes   (+-1 i8, [hi:2][pos:100][16B])    phase 4-5 (overwrites inrow/c1)
//   [800..900) pb1     (pool1 bit words)                 phase 3-4
// Block-shared: Blds[2304] = conv2 B frags (read-only after staging).
#define WSTRIDE 900   // *4 B = 3600 per wave slice
__global__ __launch_bounds__(512, 6) void k_main(const float* __restrict__ x,
                                                 const unsigned int* __restrict__ ws,
                                                 float* __restrict__ out, int B) {
    __shared__ __align__(16) unsigned int s_u[8 * WSTRIDE + 2304];

    const int tid = threadIdx.x & 63;
    const int wid = threadIdx.x >> 6;            // 0..7
    const float* wsf = (const float*)ws;
    const int*   wsi = (const int*)ws;

    unsigned int* Blds  = s_u + 8 * WSTRIDE;     // [2304] block-shared B frags
    unsigned int* bytes = s_u + wid * WSTRIDE;   // [800] (phase 4+)
    unsigned int* inrow = bytes;                 // [66]
    unsigned int* c1    = bytes + 66;            // [400]
    unsigned int* pb1   = bytes + 800;           // [100]

    // ---- stage conv2 B-fragments to block-shared LDS (once per block),
    //      BEFORE any bounds-exit so all waves reach the barrier ----
    for (int i = threadIdx.x; i < 576; i += 512)
        *(u32x4*)(Blds + i*4) = *(const u32x4*)(ws + OFF_B2 + i*4);
    __syncthreads();

    const int b = blockIdx.x * 8 + wid;
    if (b >= B) return;                          // wave-uniform exit

    const int nthr2 = wsi[OFF_T2C + (tid & 31)];

    // ---- pack input signs: one row (c,y) per lane, 1 VALU/element ----
    // bit = !signbit(v) == (v>=0) for all inputs except -0.0/NaN, which
    // jax.random.normal f32 cannot produce (|erfinv arg| >= ~2^-24).
    // alignbit(w,u,31) = (w<<1)|(u>>31); 22 chained pushes -> bits 0..21, then ~.
    for (int r = tid; r < 66; r += 64) {
        int c = r / 22, y = r - c*22;
        const float2* p = (const float2*)(x + ((size_t)b*3 + c)*484 + (size_t)y*22);
        unsigned int w = 0;
        #pragma unroll
        for (int j = 10; j >= 0; --j) {
            float2 v = p[j];
            w = __builtin_amdgcn_alignbit(w, __float_as_uint(v.y), 31);
            w = __builtin_amdgcn_alignbit(w, __float_as_uint(v.x), 31);
        }
        inrow[r] = ~w;
    }
    __builtin_amdgcn_wave_barrier();

    // ---- conv1 + BN sign: 3 VALU per (pos,och): xor, bcnt(acc=negthr), alignbit ----
    for (int pos = tid; pos < 400; pos += 64) {
        int y = pos / 20, xx = pos - y*20;
        unsigned int g = 0;
        #pragma unroll
        for (int c = 0; c < 3; ++c)
            #pragma unroll
            for (int dy = 0; dy < 3; ++dy)
                g |= ((inrow[c*22 + y + dy] >> xx) & 7u) << (c*9 + dy*3);
        unsigned int word = 0;
        #pragma unroll
        for (int o = 31; o >= 0; --o) {
            unsigned int s = (unsigned int)(__popc(g ^ ws[OFF_W1 + o]) + wsi[OFF_T1 + o]);
            word = __builtin_amdgcn_alignbit(word, s, 31);  // word=(word<<1)|(s>>31)
        }
        c1[pos] = word;
    }
    __builtin_amdgcn_wave_barrier();

    // ---- maxpool1 == OR of sign bits ----
    for (int p = tid; p < 100; p += 64) {
        int py = p / 10, px = p - py*10;
        int base = (2*py)*20 + 2*px;
        pb1[p] = c1[base] | c1[base+1] | c1[base+20] | c1[base+21];
    }
    __builtin_amdgcn_wave_barrier();

    // ---- unpack pb1 bits -> +-1 i8 bytes, layout [hi:2][pos:100][16B] ----
    // nibble spread: (nib * 0x204081) & 0x01010101 -> {0,1} bytes;
    // v_perm LUT (0x000001FF): sel 0 -> 0xFF (-1), sel 1 -> 0x01 (+1)
    #pragma unroll
    for (int i = 0; i < 4; ++i) {
        int c2 = tid + 64*i;              // chunk index: hi*100 + pos, 200 total
        if (c2 < 200) {
            int hi  = (c2 >= 100) ? 1 : 0;
            int pos = c2 - hi*100;
            unsigned int w = pb1[pos];
            int sh = hi << 4;
            u32x4 o;
            #pragma unroll
            for (int j = 0; j < 4; ++j) {
                unsigned int nib = (w >> (sh + 4*j)) & 0xFu;
                unsigned int sp  = (nib * 0x204081u) & 0x01010101u;
                o[j] = __builtin_amdgcn_perm(0u, 0x000001FFu, sp);
            }
            *(u32x4*)(bytes + c2*4) = o;
        }
    }
    __builtin_amdgcn_wave_barrier();

    // ---- conv2 via v_mfma_i32_32x32x32_i8, maxpool2 fused in-register ----
    // A: row = lane&31 = pos (quad-ordered), k-slice chunk = hi*100+pos -> ds_read_b128
    // B: from block-shared LDS, addr = s*1024 + tid*16 bytes -> ds_read_b128
    // C: col = lane&31 = och, row = (reg&3)+8*(reg>>2)+4*(lane>>5)
    //    => regs 4g..4g+3 are the 4 sub-positions of pool quad (tile*8 + 2g + hi)
    // acc starts at nthr2 so sign test is (max >= 0); ballots stay in SGPRs.
    unsigned int pb2w[16];
    {
        const int hi = tid >> 5;
        const int r  = tid & 31;
        #pragma unroll
        for (int tile = 0; tile < 2; ++tile) {
            int gq  = tile*8 + (r >> 2);           // global pool-quad 0..15
            int sub = r & 3;
            int y   = ((gq >> 2) << 1) + (sub >> 1);
            int x   = ((gq & 3) << 1) + (sub & 1);
            const v4i* __restrict__ Ab = (const v4i*)(bytes + (hi*100 + y*10 + x)*4);
            const v4i* __restrict__ Bb = (const v4i*)(Blds + tid*4);
            v16i acc;
            #pragma unroll
            for (int j = 0; j < 16; ++j) acc[j] = nthr2;
            __builtin_amdgcn_s_setprio(1);
            #pragma unroll
            for (int s = 0; s < 9; ++s) {
                int dy = s / 3, dx = s - dy*3;     // compile-time under unroll
                v4i a  = Ab[dy*10 + dx];           // ds_read_b128, const offset
                v4i bf = Bb[s*64];                 // ds_read_b128, const offset s*1024B
                acc = __builtin_amdgcn_mfma_i32_32x32x32_i8(a, bf, acc, 0, 0, 0);
            }
            __builtin_amdgcn_s_setprio(0);
            #pragma unroll
            for (int g = 0; g < 4; ++g) {
                int m0 = acc[4*g]   > acc[4*g+1] ? acc[4*g]   : acc[4*g+1];
                int m1 = acc[4*g+2] > acc[4*g+3] ? acc[4*g+2] : acc[4*g+3];
                int mx = m0 > m1 ? m0 : m1;        // pool-before-threshold (monotone BN+htanh)
                unsigned long long bal = __ballot(mx >= 0);   // wave-uniform -> SGPRs
                pb2w[tile*8 + 2*g]     = (unsigned int)bal;         // quad 2g,   och 0..31
                pb2w[tile*8 + 2*g + 1] = (unsigned int)(bal >> 32); // quad 2g+1
            }
        }
    }

    // ---- conv3 weights/threshold (post-MFMA; outside the conv2 reg peak) ----
    unsigned int w3r[9];
    #pragma unroll
    for (int k = 0; k < 9; ++k) w3r[k] = ws[OFF_W3 + tid*9 + k];
    const int negt3 = wsi[OFF_T3 + tid];

    // ---- conv3 + BN sign + pool3 -> 64-bit feature via ballot (lane = och) ----
    unsigned long long b3 = 0;
    {
        unsigned int oracc = 0;
        #pragma unroll
        for (int py = 0; py < 2; ++py)
            #pragma unroll
            for (int px = 0; px < 2; ++px) {
                int s = negt3;
                #pragma unroll
                for (int dy = 0; dy < 3; ++dy)
                    #pragma unroll
                    for (int dx = 0; dx < 3; ++dx)
                        s += __popc(pb2w[(py+dy)*4 + px + dx] ^ w3r[dy*3+dx]);
                oracc |= (unsigned int)s;          // OR of sign bits == sign of OR
            }
        b3 = __ballot((int)oracc < 0);
    }

    // ---- fc1 in registers (outputs tid, tid+64 consumed by the same lane) ----
    float h0, h1;
    {
        const unsigned long long* wfc1b = (const unsigned long long*)(ws + OFF_WFC1);
        int pc0 = __popcll(b3 ^ wfc1b[tid]);
        int pc1 = __popcll(b3 ^ wfc1b[tid + 64]);
        float p0 = fmaf((float)pc0, wsf[OFF_A4 + tid],      wsf[OFF_C4 + tid]);
        float p1 = fmaf((float)pc1, wsf[OFF_A4 + tid + 64], wsf[OFF_C4 + tid + 64]);
        h0 = fminf(1.f, fmaxf(-1.f, p0));
        h1 = fminf(1.f, fmaxf(-1.f, p1));
    }

    // ---- fc2 (softmax) / fc3 (BN) ----
    {
        float part[6];
        #pragma unroll
        for (int j = 0; j < 2; ++j)
            part[j] = h0 * wsf[OFF_WF2 + j*128 + tid] + h1 * wsf[OFF_WF2 + j*128 + 64 + tid];
        #pragma unroll
        for (int j = 0; j < 4; ++j)
            part[2+j] = h0 * wsf[OFF_WF3 + j*128 + tid] + h1 * wsf[OFF_WF3 + j*128 + 64 + tid];
        #pragma unroll
        for (int off = 32; off; off >>= 1) {
            #pragma unroll
            for (int j = 0; j < 6; ++j)
                part[j] += __shfl_xor(part[j], off);
        }
        if (tid < 6) {
            if (tid < 2) {
                float y0 = part[0]*wsf[OFF_BN5+0] + wsf[OFF_BN5+2];
                float y1 = part[1]*wsf[OFF_BN5+1] + wsf[OFF_BN5+3];
                float mx = fmaxf(y0, y1);
                float e0 = expf(y0 - mx), e1 = expf(y1 - mx);
                float r  = 1.f / (e0 + e1);
                out[(size_t)b*2 + tid] = (tid == 0 ? e0 : e1) * r;
            } else {
                int j = tid - 2;
                out[(size_t)B*2 + (size_t)b*4 + j] = part[2+j]*wsf[OFF_BN6+j] + wsf[OFF_BN6+4+j];
            }
        }
    }
}

extern "C" void kernel_launch(void* const* d_in, const int* in_sizes, int n_in,
                              void* d_out, int out_size, void* d_ws, size_t ws_size,
                              hipStream_t stream) {
    const float* x    = (const float*)d_in[0];
    const float* w1   = (const float*)d_in[1];
    const float* w2   = (const float*)d_in[2];
    const float* w3   = (const float*)d_in[3];
    const float* wfc1 = (const float*)d_in[4];
    const float* wfc2 = (const float*)d_in[5];
    const float* wfc3 = (const float*)d_in[6];
    const float* bn1  = (const float*)d_in[7];
    const float* bn2  = (const float*)d_in[8];
    const float* bn3  = (const float*)d_in[9];
    const float* bn4  = (const float*)d_in[10];
    const float* bn5  = (const float*)d_in[11];
    const float* bn6  = (const float*)d_in[12];
    unsigned int* ws  = (unsigned int*)d_ws;
    float* out        = (float*)d_out;
    int B = in_sizes[0] / 1452;   // 3*22*22

    k_prep<<<5, 256, 0, stream>>>(w1, w2, w3, wfc1, wfc2, wfc3,
                                  bn1, bn2, bn3, bn4, bn5, bn6, ws);
    k_main<<<(B + 7) / 8, 512, 0, stream>>>(x, ws, out, B);
}

// Round 12
// 178.703 us; speedup vs baseline: 1.0204x; 1.0204x over previous
//
#include <hip/hip_runtime.h>
#include <cstdint>
#include <cmath>

typedef int  v4i  __attribute__((ext_vector_type(4)));
typedef int  v16i __attribute__((ext_vector_type(16)));
typedef unsigned int u32x4 __attribute__((ext_vector_type(4)));

// ---- d_ws layout (4-byte words) ----
// Thresholds on popcount stored as negthr = -(thr+1):  pc <= thr  <=>  (pc + negthr) < 0
// Thresholds on c (MFMA path) stored as nthr2 = -ceil(t):  c >= t  <=>  (c + nthr2) >= 0
#define OFF_W1   0      // 32  u32: conv1 weight bits (27 bits: c*9+dy*3+dx)
#define OFF_T1   32     // 32  i32: conv1 negthr (popcount domain)
#define OFF_W3   384    // 576 u32: conv3 weight bits [o][k]
#define OFF_T3   960    // 64  i32: conv3 negthr (popcount domain)
#define OFF_WFC1 1024   // 256 u32: fc1 weight bits, 2 words per output (64 bits)
#define OFF_A4   1280   // 128 f32: h = clip(pc*a4 + c4, -1, 1)
#define OFF_C4   1408   // 128 f32
#define OFF_WF2  1536   // 256 f32: w_fc2 [2][128]
#define OFF_WF3  1792   // 512 f32: w_fc3 [4][128]
#define OFF_BN5  2304   // 4 f32: inv5[2], d5[2]
#define OFF_BN6  2308   // 8 f32: inv6[4], d6[4]
#define OFF_B2   2560   // 2304 u32: conv2 i8-MFMA B frags [s:9][lane:64][reg:4], bytes = +-1
#define OFF_T2C  4864   // 32  i32: conv2 nthr2 = -ceil(t) on preactivation c

__device__ __forceinline__ int thr_neg(double nterms, double g, double b, double m, double v) {
    double inv = g / sqrt(v + 1e-5);
    double t = m - b / inv;                   // bit=1  <=>  c >= t   (inv > 0)
    double thr = floor((nterms - t) * 0.5);   // c = nterms - 2*pc  =>  pc <= thr
    if (thr < -2147000000.0) thr = -2147000000.0;
    if (thr >  2147000000.0) thr =  2147000000.0;
    return -((int)thr + 1);                   // sign(pc + negthr) == (pc <= thr)
}

// threshold directly on integer preactivation c: bit = (c >= t) <=> (c >= ceil(t))
__device__ __forceinline__ int thr_c_neg(double g, double b, double m, double v) {
    double inv = g / sqrt(v + 1e-5);
    double t = m - b / inv;                   // inv > 0 in this problem (gamma in [0.5,1.5])
    double ct = ceil(t);
    if (ct < -2147000000.0) ct = -2147000000.0;
    if (ct >  2147000000.0) ct =  2147000000.0;
    return -(int)ct;                          // c + nthr2 >= 0  <=>  bit = 1
}

// 5 blocks x 256 threads. Coalesced global->LDS staging, then pack from LDS.
__global__ void k_prep(const float* __restrict__ w1, const float* __restrict__ w2,
                       const float* __restrict__ w3, const float* __restrict__ wfc1,
                       const float* __restrict__ wfc2, const float* __restrict__ wfc3,
                       const float* __restrict__ bn1, const float* __restrict__ bn2,
                       const float* __restrict__ bn3, const float* __restrict__ bn4,
                       const float* __restrict__ bn5, const float* __restrict__ bn6,
                       unsigned int* __restrict__ ws) {
    __shared__ float stage[9216];
    int t = threadIdx.x;
    int blk = blockIdx.x;
    float* wsf = (float*)ws;
    int*   wsi = (int*)ws;

    if (blk == 0) {
        for (int i = t; i < 864; i += 256) stage[i] = w1[i];
        __syncthreads();
        if (t < 32) {
            unsigned int bits = 0;
            for (int j = 0; j < 27; ++j) bits |= (stage[t*27+j] >= 0.f ? 1u : 0u) << j;
            ws[OFF_W1 + t] = bits;
            wsi[OFF_T1 + t]  = thr_neg(27.0, bn1[t], bn1[32+t], bn1[64+t], bn1[96+t]);
            wsi[OFF_T2C + t] = thr_c_neg(bn2[t], bn2[32+t], bn2[64+t], bn2[96+t]);
        }
        for (int i = t; i < 256; i += 256) wsf[OFF_WF2 + i] = wfc2[i];
        for (int i = t; i < 512; i += 256) wsf[OFF_WF3 + i] = wfc3[i];
        if (t < 2) {
            float g = bn5[t], b = bn5[2+t], m = bn5[4+t], v = bn5[6+t];
            float inv = g / sqrtf(v + 1e-5f);
            wsf[OFF_BN5 + t]     = inv;
            wsf[OFF_BN5 + 2 + t] = b - m * inv;
        }
        if (t >= 4 && t < 8) {
            int j = t - 4;
            float g = bn6[j], b = bn6[4+j], m = bn6[8+j], v = bn6[12+j];
            float inv = g / sqrtf(v + 1e-5f);
            wsf[OFF_BN6 + j]     = inv;
            wsf[OFF_BN6 + 4 + j] = b - m * inv;
        }
    } else if (blk == 1) {
        // conv2 weights -> i8 MFMA B fragments (+-1 bytes), layout for
        // v_mfma_i32_32x32x32_i8: col = lane&31 = och, k = 16*(lane>>5) + reg*4 + byte,
        // global K order: k = (dy*3+dx)*32 + ic  (step s = dy*3+dx, K=288 = 9 steps)
        for (int i = t; i < 9216; i += 256) stage[i] = w2[i];
        __syncthreads();
        for (int idx = t; idx < 2304; idx += 256) {
            int s   = idx >> 8;          // K-step 0..8  (= dy*3+dx)
            int rem = idx & 255;
            int l   = rem >> 2;          // lane 0..63
            int reg = rem & 3;
            int och = l & 31;
            int icb = ((l >> 5) << 4) + (reg << 2);
            unsigned int wv = 0;
            #pragma unroll
            for (int j = 0; j < 4; ++j) {
                int ic = icb + j;
                unsigned int by = (stage[(och*32 + ic)*9 + s] >= 0.f) ? 0x01u : 0xFFu;
                wv |= by << (8*j);
            }
            ws[OFF_B2 + idx] = wv;
        }
    } else if (blk == 2 || blk == 3) {
        int base = (blk - 2) * 9216;
        for (int i = t; i < 9216; i += 256) stage[i] = w3[base + i];
        __syncthreads();
        for (int idx = t; idx < 288; idx += 256) {
            int o = idx / 9, k = idx - o*9;
            unsigned int bits = 0;
            for (int i = 0; i < 32; ++i)
                bits |= (stage[(o*32+i)*9 + k] >= 0.f ? 1u : 0u) << i;
            ws[OFF_W3 + base/32 + idx] = bits;   // base/32 = 0 or 288
        }
    } else {
        for (int i = t; i < 8192; i += 256) stage[i] = wfc1[i];
        __syncthreads();
        if (t < 128) {
            unsigned int lo = 0, hi = 0;
            for (int j = 0; j < 32; ++j) lo |= (stage[t*64+j]    >= 0.f ? 1u : 0u) << j;
            for (int j = 0; j < 32; ++j) hi |= (stage[t*64+32+j] >= 0.f ? 1u : 0u) << j;
            ws[OFF_WFC1 + 2*t]     = lo;
            ws[OFF_WFC1 + 2*t + 1] = hi;
            float g = bn4[t], b = bn4[128+t], m = bn4[256+t], v = bn4[384+t];
            float inv = g / sqrtf(v + 1e-5f);
            wsf[OFF_A4 + t] = -2.f * inv;                 // c = 64 - 2*pc
            wsf[OFF_C4 + t] = (64.f - m) * inv + b;
        }
        if (t >= 128 && t < 192) {
            int j = t - 128;
            wsi[OFF_T3 + j] = thr_neg(288.0, bn3[j], bn3[64+j], bn3[128+j], bn3[192+j]);
        }
    }
}

// 8 waves/block (512 thd), one image per wave, per-image dispatch (R11 config,
// passed, VGPR=36 spill-free). R12 change: FUSE conv1+maxpool1+unpack into ONE
// register-resident phase. R2-R11 showed dur pinned ~57us across occupancy
// 27-62% -> the wall is the per-wave serial phase chain (6 phases, each an LDS
// write->waitcnt->read round-trip) + ~160 DS ops/wave, not wave count.
// Per lane: one pool QUAD (100 quads, 2 iters): shared-row gather (12 ds_read
// vs 36), per-och min-of-4 preactivations (OR of sign bits == sign of min,
// same threshold), pooled word stays in REGISTER and is expanded to +-1 bytes
// immediately. Eliminates: c1 array, pool1 phase, pb1 round-trip, 2 barriers.
// LDS transitions 4 -> 2 (pack->gather; bytes->conv2). DS ops ~160 -> ~105.
//
// LDS per wave slice (dwords):
//   [0..66)     inrow  (input sign bits; padded to 68 for 16B alignment)
//   [68..868)   bytes  (+-1 i8, [hi:2][quad:100][16B]) — no longer aliases inrow
// Block-shared: Blds[2304] = conv2 B frags (read-only after staging).
#define WSTRIDE 868   // 68 + 800 dwords; bytes base 68*4=272B (16B-aligned)
__global__ __launch_bounds__(512, 6) void k_main(const float* __restrict__ x,
                                                 const unsigned int* __restrict__ ws,
                                                 float* __restrict__ out, int B) {
    __shared__ __align__(16) unsigned int s_u[8 * WSTRIDE + 2304];

    const int tid = threadIdx.x & 63;
    const int wid = threadIdx.x >> 6;            // 0..7
    const float* wsf = (const float*)ws;
    const int*   wsi = (const int*)ws;

    unsigned int* Blds  = s_u + 8 * WSTRIDE;     // [2304] block-shared B frags
    unsigned int* inrow = s_u + wid * WSTRIDE;   // [66]
    unsigned int* bytes = inrow + 68;            // [800]

    // ---- stage conv2 B-fragments to block-shared LDS (once per block),
    //      BEFORE any bounds-exit so all waves reach the barrier ----
    for (int i = threadIdx.x; i < 576; i += 512)
        *(u32x4*)(Blds + i*4) = *(const u32x4*)(ws + OFF_B2 + i*4);
    __syncthreads();

    const int b = blockIdx.x * 8 + wid;
    if (b >= B) return;                          // wave-uniform exit

    const int nthr2 = wsi[OFF_T2C + (tid & 31)];

    // ---- pack input signs: one row (c,y) per lane, 1 VALU/element ----
    // bit = !signbit(v) == (v>=0) for all inputs except -0.0/NaN, which
    // jax.random.normal f32 cannot produce (|erfinv arg| >= ~2^-24).
    // alignbit(w,u,31) = (w<<1)|(u>>31); 22 chained pushes -> bits 0..21, then ~.
    for (int r = tid; r < 66; r += 64) {
        int c = r / 22, y = r - c*22;
        const float2* p = (const float2*)(x + ((size_t)b*3 + c)*484 + (size_t)y*22);
        unsigned int w = 0;
        #pragma unroll
        for (int j = 10; j >= 0; --j) {
            float2 v = p[j];
            w = __builtin_amdgcn_alignbit(w, __float_as_uint(v.y), 31);
            w = __builtin_amdgcn_alignbit(w, __float_as_uint(v.x), 31);
        }
        inrow[r] = ~w;
    }
    __builtin_amdgcn_wave_barrier();

    // ---- FUSED conv1 + BN sign + maxpool1 + unpack (register-resident) ----
    // Lane owns quad q = (py,px): conv positions (2py+dy, 2px+dx), dy,dx in {0,1}.
    // Shared-row gather: rows c*22+2py+d, d=0..3 cover all 4 positions (12 reads).
    // OR of sign bits over the quad == sign of min of the 4 preactivations
    // (identical negthr for all 4). Pooled word pw -> +-1 bytes directly.
    #pragma unroll
    for (int it = 0; it < 2; ++it) {
        int q = tid + 64*it;                   // quad index, 100 total
        if (q < 100) {
            int py = q / 10, px = q - py*10;
            unsigned int g00 = 0, g01 = 0, g10 = 0, g11 = 0;   // g[dy][dx]
            #pragma unroll
            for (int c = 0; c < 3; ++c) {
                unsigned int a0, a1, a2, a3, b0, b1, b2, b3;
                {
                    unsigned int w0 = (inrow[c*22 + 2*py + 0] >> (2*px)) & 15u;
                    unsigned int w1 = (inrow[c*22 + 2*py + 1] >> (2*px)) & 15u;
                    unsigned int w2 = (inrow[c*22 + 2*py + 2] >> (2*px)) & 15u;
                    unsigned int w3 = (inrow[c*22 + 2*py + 3] >> (2*px)) & 15u;
                    a0 = w0 & 7u; b0 = (w0 >> 1) & 7u;
                    a1 = w1 & 7u; b1 = (w1 >> 1) & 7u;
                    a2 = w2 & 7u; b2 = (w2 >> 1) & 7u;
                    a3 = w3 & 7u; b3 = (w3 >> 1) & 7u;
                }
                int sh = c*9;
                g00 |= (a0 | (a1 << 3) | (a2 << 6)) << sh;
                g10 |= (a1 | (a2 << 3) | (a3 << 6)) << sh;
                g01 |= (b0 | (b1 << 3) | (b2 << 6)) << sh;
                g11 |= (b1 | (b2 << 3) | (b3 << 6)) << sh;
            }
            unsigned int pw = 0;
            #pragma unroll
            for (int o = 31; o >= 0; --o) {
                unsigned int wv = ws[OFF_W1 + o];
                int t0 = wsi[OFF_T1 + o];
                int s0 = __popc(g00 ^ wv) + t0;
                int s1 = __popc(g01 ^ wv) + t0;
                int s2 = __popc(g10 ^ wv) + t0;
                int s3 = __popc(g11 ^ wv) + t0;
                int m0 = s0 < s1 ? s0 : s1;
                int m1 = s2 < s3 ? s2 : s3;
                int mn = m0 < m1 ? m0 : m1;        // sign(mn) == OR of 4 sign bits
                pw = __builtin_amdgcn_alignbit(pw, (unsigned int)mn, 31);
            }
            // unpack pw -> +-1 i8 bytes, both K-halves, straight from register.
            // nibble spread: (nib*0x204081)&0x01010101 -> {0,1} bytes;
            // v_perm LUT (0x000001FF): sel 0 -> 0xFF (-1), sel 1 -> 0x01 (+1)
            #pragma unroll
            for (int hi = 0; hi < 2; ++hi) {
                int sh = hi << 4;
                u32x4 o4;
                #pragma unroll
                for (int j = 0; j < 4; ++j) {
                    unsigned int nib = (pw >> (sh + 4*j)) & 0xFu;
                    o4[j] = __builtin_amdgcn_perm(0u, 0x000001FFu, (nib * 0x204081u) & 0x01010101u);
                }
                *(u32x4*)(bytes + (hi*100 + q)*4) = o4;
            }
        }
    }
    __builtin_amdgcn_wave_barrier();

    // ---- conv2 via v_mfma_i32_32x32x32_i8, maxpool2 fused in-register ----
    // A: row = lane&31 = pos (quad-ordered), k-slice chunk = hi*100+pos -> ds_read_b128
    // B: from block-shared LDS, addr = s*1024 + tid*16 bytes -> ds_read_b128
    // C: col = lane&31 = och, row = (reg&3)+8*(reg>>2)+4*(lane>>5)
    //    => regs 4g..4g+3 are the 4 sub-positions of pool quad (tile*8 + 2g + hi)
    // acc starts at nthr2 so sign test is (max >= 0); ballots stay in SGPRs.
    unsigned int pb2w[16];
    {
        const int hi = tid >> 5;
        const int r  = tid & 31;
        #pragma unroll
        for (int tile = 0; tile < 2; ++tile) {
            int gq  = tile*8 + (r >> 2);           // global pool-quad 0..15
            int sub = r & 3;
            int y   = ((gq >> 2) << 1) + (sub >> 1);
            int x   = ((gq & 3) << 1) + (sub & 1);
            const v4i* __restrict__ Ab = (const v4i*)(bytes + (hi*100 + y*10 + x)*4);
            const v4i* __restrict__ Bb = (const v4i*)(Blds + tid*4);
            v16i acc;
            #pragma unroll
            for (int j = 0; j < 16; ++j) acc[j] = nthr2;
            __builtin_amdgcn_s_setprio(1);
            #pragma unroll
            for (int s = 0; s < 9; ++s) {
                int dy = s / 3, dx = s - dy*3;     // compile-time under unroll
                v4i a  = Ab[dy*10 + dx];           // ds_read_b128, const offset
                v4i bf = Bb[s*64];                 // ds_read_b128, const offset s*1024B
                acc = __builtin_amdgcn_mfma_i32_32x32x32_i8(a, bf, acc, 0, 0, 0);
            }
            __builtin_amdgcn_s_setprio(0);
            #pragma unroll
            for (int g = 0; g < 4; ++g) {
                int m0 = acc[4*g]   > acc[4*g+1] ? acc[4*g]   : acc[4*g+1];
                int m1 = acc[4*g+2] > acc[4*g+3] ? acc[4*g+2] : acc[4*g+3];
                int mx = m0 > m1 ? m0 : m1;        // pool-before-threshold (monotone BN+htanh)
                unsigned long long bal = __ballot(mx >= 0);   // wave-uniform -> SGPRs
                pb2w[tile*8 + 2*g]     = (unsigned int)bal;         // quad 2g,   och 0..31
                pb2w[tile*8 + 2*g + 1] = (unsigned int)(bal >> 32); // quad 2g+1
            }
        }
    }

    // ---- conv3 weights/threshold (post-MFMA; outside the conv2 reg peak) ----
    unsigned int w3r[9];
    #pragma unroll
    for (int k = 0; k < 9; ++k) w3r[k] = ws[OFF_W3 + tid*9 + k];
    const int negt3 = wsi[OFF_T3 + tid];

    // ---- conv3 + BN sign + pool3 -> 64-bit feature via ballot (lane = och) ----
    unsigned long long b3 = 0;
    {
        unsigned int oracc = 0;
        #pragma unroll
        for (int py = 0; py < 2; ++py)
            #pragma unroll
            for (int px = 0; px < 2; ++px) {
                int s = negt3;
                #pragma unroll
                for (int dy = 0; dy < 3; ++dy)
                    #pragma unroll
                    for (int dx = 0; dx < 3; ++dx)
                        s += __popc(pb2w[(py+dy)*4 + px + dx] ^ w3r[dy*3+dx]);
                oracc |= (unsigned int)s;          // OR of sign bits == sign of OR
            }
        b3 = __ballot((int)oracc < 0);
    }

    // ---- fc1 in registers (outputs tid, tid+64 consumed by the same lane) ----
    float h0, h1;
    {
        const unsigned long long* wfc1b = (const unsigned long long*)(ws + OFF_WFC1);
        int pc0 = __popcll(b3 ^ wfc1b[tid]);
        int pc1 = __popcll(b3 ^ wfc1b[tid + 64]);
        float p0 = fmaf((float)pc0, wsf[OFF_A4 + tid],      wsf[OFF_C4 + tid]);
        float p1 = fmaf((float)pc1, wsf[OFF_A4 + tid + 64], wsf[OFF_C4 + tid + 64]);
        h0 = fminf(1.f, fmaxf(-1.f, p0));
        h1 = fminf(1.f, fmaxf(-1.f, p1));
    }

    // ---- fc2 (softmax) / fc3 (BN) ----
    {
        float part[6];
        #pragma unroll
        for (int j = 0; j < 2; ++j)
            part[j] = h0 * wsf[OFF_WF2 + j*128 + tid] + h1 * wsf[OFF_WF2 + j*128 + 64 + tid];
        #pragma unroll
        for (int j = 0; j < 4; ++j)
            part[2+j] = h0 * wsf[OFF_WF3 + j*128 + tid] + h1 * wsf[OFF_WF3 + j*128 + 64 + tid];
        #pragma unroll
        for (int off = 32; off; off >>= 1) {
            #pragma unroll
            for (int j = 0; j < 6; ++j)
                part[j] += __shfl_xor(part[j], off);
        }
        if (tid < 6) {
            if (tid < 2) {
                float y0 = part[0]*wsf[OFF_BN5+0] + wsf[OFF_BN5+2];
                float y1 = part[1]*wsf[OFF_BN5+1] + wsf[OFF_BN5+3];
                float mx = fmaxf(y0, y1);
                float e0 = expf(y0 - mx), e1 = expf(y1 - mx);
                float r  = 1.f / (e0 + e1);
                out[(size_t)b*2 + tid] = (tid == 0 ? e0 : e1) * r;
            } else {
                int j = tid - 2;
                out[(size_t)B*2 + (size_t)b*4 + j] = part[2+j]*wsf[OFF_BN6+j] + wsf[OFF_BN6+4+j];
            }
        }
    }
}

extern "C" void kernel_launch(void* const* d_in, const int* in_sizes, int n_in,
                              void* d_out, int out_size, void* d_ws, size_t ws_size,
                              hipStream_t stream) {
    const float* x    = (const float*)d_in[0];
    const float* w1   = (const float*)d_in[1];
    const float* w2   = (const float*)d_in[2];
    const float* w3   = (const float*)d_in[3];
    const float* wfc1 = (const float*)d_in[4];
    const float* wfc2 = (const float*)d_in[5];
    const float* wfc3 = (const float*)d_in[6];
    const float* bn1  = (const float*)d_in[7];
    const float* bn2  = (const float*)d_in[8];
    const float* bn3  = (const float*)d_in[9];
    const float* bn4  = (const float*)d_in[10];
    const float* bn5  = (const float*)d_in[11];
    const float* bn6  = (const float*)d_in[12];
    unsigned int* ws  = (unsigned int*)d_ws;
    float* out        = (float*)d_out;
    int B = in_sizes[0] / 1452;   // 3*22*22

    k_prep<<<5, 256, 0, stream>>>(w1, w2, w3, wfc1, wfc2, wfc3,
                                  bn1, bn2, bn3, bn4, bn5, bn6, ws);
    k_main<<<(B + 7) / 8, 512, 0, stream>>>(x, ws, out, B);
}